// Round 13
// baseline (96.853 us; speedup 1.0000x reference)
//
#include <hip/hip_runtime.h>
#include <hip/hip_bf16.h>

// Round 13: remove the P LDS round-trip. S^T's C-layout (lane holds keys
// quad*4+reg for query l16) IS the 16x16x16-MFMA A-fragment layout
// (A[m=l16][k=quad*4+j]) -> exp+pack in-lane, PV via K=16 MFMAs, V as plain
// b64 B-frags. Main loop has ZERO LDS ops. Merge epilogue unchanged (r12).

#define LSP   576
#define NROW  9216
#define DH    32
#define NW    16              // waves per attn block
#define KPW   (NROW / NW)     // 576 keys per wave
#define NST   18              // 18 x 32-key subtiles per wave
#define QB    36              // queries per attn block (grid = 256 exactly)
#define SZ    ((size_t)NROW * DH)
#define SZP   (SZ + 4096)     // pad: ghost-row reads stay in-bounds

typedef __attribute__((ext_vector_type(8))) short bh8;
typedef __attribute__((ext_vector_type(4))) short bh4;
typedef __attribute__((ext_vector_type(4))) float f4;

static __device__ __forceinline__ unsigned short f2bf(float x) {
    union { float f; unsigned int i; } w; w.f = x;
    unsigned int u = w.i;
    return (unsigned short)((u + 0x7fffu + ((u >> 16) & 1u)) >> 16);
}
static __device__ __forceinline__ unsigned int pkbf(float a, float b) {
    union { __hip_bfloat162 h2; unsigned int u; } w;
    w.h2 = __float22bfloat162_rn(make_float2(a, b));   // a -> low ushort (RNE)
    return w.u;
}
static __device__ __forceinline__ bh4 pack4(float a, float b, float c, float d) {
    union { unsigned int u[2]; bh4 v; } w;
    w.u[0] = pkbf(a, b); w.u[1] = pkbf(c, d);
    return w.v;
}
static __device__ __forceinline__ float fexp2(float x) {
#if __has_builtin(__builtin_amdgcn_exp2f)
    return __builtin_amdgcn_exp2f(x);
#else
    return exp2f(x);
#endif
}

#define MFMA(a, b, c) __builtin_amdgcn_mfma_f32_16x16x32_bf16(a, b, c, 0, 0, 0)

#if __has_builtin(__builtin_amdgcn_mfma_f32_16x16x16bf16_1k)
#define MFMA16(a, b, c) __builtin_amdgcn_mfma_f32_16x16x16bf16_1k(a, b, c, 0, 0, 0)
#else
// exact fallback: zero-pad upper K of a 16x16x32 MFMA (0 * anything = 0)
static __device__ __forceinline__ bh8 pad8(bh4 x) {
    bh8 r = {x[0], x[1], x[2], x[3], 0, 0, 0, 0};
    return r;
}
#define MFMA16(a, b, c) __builtin_amdgcn_mfma_f32_16x16x32_bf16(pad8(a), pad8(b), c, 0, 0, 0)
#endif

// ---------------- projections + PE -> Qhi/Khi [n][32], Vt [n>>5][d][n&31] ---
// Q pre-scaled by 1/sqrt(d)*log2(e) (exp2-folded softmax). V tiles plain.
__global__ __launch_bounds__(256) void sa_proj_kernel(
    const float* __restrict__ x,
    const float* __restrict__ wq, const float* __restrict__ wk, const float* __restrict__ wv,
    unsigned short* __restrict__ Qhi, unsigned short* __restrict__ Khi,
    unsigned short* __restrict__ Vt)
{
    __shared__ __align__(16) float xs[32 * 40];
    __shared__ float vt[32 * 37];
    __shared__ float wqs[32 * 33], wks[32 * 33], wvs[32 * 33];
    const int t = threadIdx.x;
    const int bg = blockIdx.x >> 4;
    const int part = blockIdx.x & 15;
    const int g = bg & 7;
    const int l0 = part * 36;

    const float* xp = x + (size_t)bg * 32 * LSP + l0;
    for (int i = t; i < 32 * 9; i += 256) {
        int d = i / 9, seg = i % 9;
        *(float4*)(xs + d * 40 + seg * 4) = *(const float4*)(xp + d * LSP + seg * 4);
    }
    for (int i = t; i < 1024; i += 256) {
        int o = i >> 5, d = i & 31;
        wqs[o * 33 + d] = wq[(g * 32 + o) * 32 + d];
        wks[o * 33 + d] = wk[(g * 32 + o) * 32 + d];
        wvs[o * 33 + d] = wv[(g * 32 + o) * 32 + d];
    }
    __syncthreads();

    const float scale = 0.17677669529663687f * 1.4426950408889634f;  // /sqrt(32)*log2(e)
    for (int idx = t; idx < 32 * 36; idx += 256) {
        const int o = idx & 31;
        const int lloc = idx >> 5;
        const int l = l0 + lloc;
        float aq = 0.f, ak = 0.f, av = 0.f;
        #pragma unroll
        for (int d = 0; d < 32; d++) {
            const float xv = xs[d * 40 + lloc];
            aq = fmaf(wqs[o * 33 + d], xv, aq);
            ak = fmaf(wks[o * 33 + d], xv, ak);
            av = fmaf(wvs[o * 33 + d], xv, av);
        }
        aq *= scale;
        const int c = g * 32 + o;
        const float i2 = (float)(c & ~1);
        const float inv = __expf(-0.035977892078031968f * i2);   // ln(1e4)/256
        float sv, cv;
        __sincosf(inv * (float)l, &sv, &cv);
        ak += (c & 1) ? cv : sv;

        const size_t row = (size_t)bg * LSP + l;
        Qhi[row * 32 + o] = f2bf(aq);
        Khi[row * 32 + o] = f2bf(ak);
        vt[o * 37 + lloc] = av;
    }
    __syncthreads();

    for (int idx = t; idx < 32 * 36; idx += 256) {     // plain V tile write
        const int d = idx / 36;
        const int cc = idx - d * 36;
        const int n = bg * LSP + l0 + cc;
        Vt[(size_t)(n >> 5) * 1024 + d * 32 + (n & 31)] = f2bf(vt[d * 37 + cc]);
    }
}

// ---------------- fused attention: register-only main loop ------------------
// grid 256 x 1024 threads = 16 waves; block owns QB=36 queries (rows 36..47
// ghosts); wave w owns keys [w*576,(w+1)*576), 18 x 32-key subtiles.
__global__ __launch_bounds__(1024, 4) void sa_attn_kernel(
    const unsigned short* __restrict__ Qhi, const unsigned short* __restrict__ Khi,
    const unsigned short* __restrict__ Vt, float* __restrict__ out)
{
    __shared__ float shm[8 * 1536 + 8 * 48];   // merge planes only (50.7 KB)
    const int t = threadIdx.x;
    const int wave = t >> 6, lane = t & 63;
    const int quad = lane >> 4, l16 = lane & 15;
    const int n0 = blockIdx.x * QB;

    // Q B-fragments (3 row-groups of 16; rows 36..47 are ghosts -> tiny poison)
    const bh8 qh0 = *(const bh8*)(Qhi + (size_t)(n0 + l16) * DH + quad * 8);
    const bh8 qh1 = *(const bh8*)(Qhi + (size_t)(n0 + 16 + l16) * DH + quad * 8);
    const bh8 qh2 = *(const bh8*)(Qhi + (size_t)(n0 + 32 + l16) * DH + quad * 8);

    f4 o00 = {0.f,0.f,0.f,0.f}, o01 = {0.f,0.f,0.f,0.f};
    f4 o10 = {0.f,0.f,0.f,0.f}, o11 = {0.f,0.f,0.f,0.f};
    f4 o20 = {0.f,0.f,0.f,0.f}, o21 = {0.f,0.f,0.f,0.f};
    float ls0 = 0.f, ls1 = 0.f, ls2 = 0.f;
    const f4 zf = {0.f,0.f,0.f,0.f};

    const int kbase = wave * KPW;
    const int tb = kbase >> 5;                 // base 32-key tile index

    // prefetch subtile 0: K A-frags (b128) + V B-frags (b64, plain layout)
    bh8 kf0 = *(const bh8*)(Khi + (size_t)(kbase + l16) * DH + quad * 8);
    bh8 kf1 = *(const bh8*)(Khi + (size_t)(kbase + 16 + l16) * DH + quad * 8);
    const unsigned short* vb = Vt + (size_t)tb * 1024;
    bh4 vl0 = *(const bh4*)(vb + l16 * 32 + quad * 4);              // keys-lo, d-lo
    bh4 vh0 = *(const bh4*)(vb + l16 * 32 + 16 + quad * 4);         // keys-hi, d-lo
    bh4 vl1 = *(const bh4*)(vb + (16 + l16) * 32 + quad * 4);       // keys-lo, d-hi
    bh4 vh1 = *(const bh4*)(vb + (16 + l16) * 32 + 16 + quad * 4);  // keys-hi, d-hi

    for (int st = 0; st < NST; ++st) {
        const int ns = (st + 1 < NST) ? st + 1 : st;

        // issue next subtile's loads first (distance-1 prefetch into temps)
        const unsigned short* kp = Khi + (size_t)(kbase + ns * 32) * DH;
        const bh8 nk0 = *(const bh8*)(kp + (size_t)l16 * DH + quad * 8);
        const bh8 nk1 = *(const bh8*)(kp + (size_t)(16 + l16) * DH + quad * 8);
        const unsigned short* nvb = Vt + (size_t)(tb + ns) * 1024;
        const bh4 nvl0 = *(const bh4*)(nvb + l16 * 32 + quad * 4);
        const bh4 nvh0 = *(const bh4*)(nvb + l16 * 32 + 16 + quad * 4);
        const bh4 nvl1 = *(const bh4*)(nvb + (16 + l16) * 32 + quad * 4);
        const bh4 nvh1 = *(const bh4*)(nvb + (16 + l16) * 32 + 16 + quad * 4);

        // S^T = K.Q^T: lane (quad,l16) holds P[query=l16][key=quad*4+reg] (+16)
        const f4 s00 = MFMA(kf0, qh0, zf);
        const f4 s10 = MFMA(kf1, qh0, zf);
        const f4 s01 = MFMA(kf0, qh1, zf);
        const f4 s11 = MFMA(kf1, qh1, zf);
        const f4 s02 = MFMA(kf0, qh2, zf);
        const f4 s12 = MFMA(kf1, qh2, zf);

        // qgroup 0: exp + in-lane pack (= K=16 A-frag) + PV
        {
            const float a = fexp2(s00[0]), b = fexp2(s00[1]),
                        c = fexp2(s00[2]), d = fexp2(s00[3]);
            const float e = fexp2(s10[0]), f = fexp2(s10[1]),
                        g = fexp2(s10[2]), h = fexp2(s10[3]);
            ls0 += ((a + b) + (c + d)) + ((e + f) + (g + h));
            const bh4 alo = pack4(a, b, c, d);
            const bh4 ahi = pack4(e, f, g, h);
            o00 = MFMA16(alo, vl0, o00); o00 = MFMA16(ahi, vh0, o00);
            o01 = MFMA16(alo, vl1, o01); o01 = MFMA16(ahi, vh1, o01);
        }
        // qgroup 1
        {
            const float a = fexp2(s01[0]), b = fexp2(s01[1]),
                        c = fexp2(s01[2]), d = fexp2(s01[3]);
            const float e = fexp2(s11[0]), f = fexp2(s11[1]),
                        g = fexp2(s11[2]), h = fexp2(s11[3]);
            ls1 += ((a + b) + (c + d)) + ((e + f) + (g + h));
            const bh4 alo = pack4(a, b, c, d);
            const bh4 ahi = pack4(e, f, g, h);
            o10 = MFMA16(alo, vl0, o10); o10 = MFMA16(ahi, vh0, o10);
            o11 = MFMA16(alo, vl1, o11); o11 = MFMA16(ahi, vh1, o11);
        }
        // qgroup 2 (rows 32..35 real, 36..47 ghosts)
        {
            const float a = fexp2(s02[0]), b = fexp2(s02[1]),
                        c = fexp2(s02[2]), d = fexp2(s02[3]);
            const float e = fexp2(s12[0]), f = fexp2(s12[1]),
                        g = fexp2(s12[2]), h = fexp2(s12[3]);
            ls2 += ((a + b) + (c + d)) + ((e + f) + (g + h));
            const bh4 alo = pack4(a, b, c, d);
            const bh4 ahi = pack4(e, f, g, h);
            o20 = MFMA16(alo, vl0, o20); o20 = MFMA16(ahi, vh0, o20);
            o21 = MFMA16(alo, vl1, o21); o21 = MFMA16(ahi, vh1, o21);
        }

        // rotate prefetched regs in
        kf0 = nk0; kf1 = nk1;
        vl0 = nvl0; vh0 = nvh0; vl1 = nvl1; vh1 = nvh1;
    }

    // per-wave row sums: reduce across the 4 quads (full key range of wave)
    ls0 += __shfl_xor(ls0, 16); ls0 += __shfl_xor(ls0, 32);
    ls1 += __shfl_xor(ls1, 16); ls1 += __shfl_xor(ls1, 32);
    ls2 += __shfl_xor(ls2, 16); ls2 += __shfl_xor(ls2, 32);

    // two-stage additive merge: waves 0..7 write planes, waves 8..15 add in
    float* mo = shm;                 // [8][32*48]
    float* mls = mo + 8 * 1536;      // [8][48]
    const int mw = wave & 7;
    float* mp = mo + mw * 1536;
    if (wave < 8) {
        #pragma unroll
        for (int reg = 0; reg < 4; ++reg) {
            const int q0 = quad * 4 + reg;   // O C-layout: row=query, col=d=l16
            mp[l16 * 48 + q0]             = o00[reg];
            mp[(16 + l16) * 48 + q0]      = o01[reg];
            mp[l16 * 48 + 16 + q0]        = o10[reg];
            mp[(16 + l16) * 48 + 16 + q0] = o11[reg];
            mp[l16 * 48 + 32 + q0]        = o20[reg];
            mp[(16 + l16) * 48 + 32 + q0] = o21[reg];
        }
        if (quad == 0) {
            mls[mw * 48 + l16]      = ls0;
            mls[mw * 48 + 16 + l16] = ls1;
            mls[mw * 48 + 32 + l16] = ls2;
        }
    }
    __syncthreads();
    if (wave >= 8) {
        #pragma unroll
        for (int reg = 0; reg < 4; ++reg) {
            const int q0 = quad * 4 + reg;
            mp[l16 * 48 + q0]             += o00[reg];
            mp[(16 + l16) * 48 + q0]      += o01[reg];
            mp[l16 * 48 + 16 + q0]        += o10[reg];
            mp[(16 + l16) * 48 + 16 + q0] += o11[reg];
            mp[l16 * 48 + 32 + q0]        += o20[reg];
            mp[(16 + l16) * 48 + 32 + q0] += o21[reg];
        }
        if (quad == 0) {
            mls[mw * 48 + l16]      += ls0;
            mls[mw * 48 + 16 + l16] += ls1;
            mls[mw * 48 + 32 + l16] += ls2;
        }
    }
    __syncthreads();

    const int bg = n0 / LSP;
    const int l0 = n0 - bg * LSP;
    for (int c = t; c < 32 * QB; c += 1024) {
        const int d = c / QB;
        const int q = c - d * QB;
        float num = 0.f, den = 0.f;
        #pragma unroll
        for (int w2 = 0; w2 < 8; ++w2) {
            num += mo[w2 * 1536 + d * 48 + q];
            den += mls[w2 * 48 + q];
        }
        out[((size_t)(bg * 32 + d)) * LSP + l0 + q] = num / den;
    }
}

extern "C" void kernel_launch(void* const* d_in, const int* in_sizes, int n_in,
                              void* d_out, int out_size, void* d_ws, size_t ws_size,
                              hipStream_t stream) {
    (void)in_sizes; (void)n_in; (void)out_size; (void)ws_size;
    const float* x  = (const float*)d_in[0];
    const float* wq = (const float*)d_in[1];
    const float* wk = (const float*)d_in[2];
    const float* wv = (const float*)d_in[3];

    unsigned short* ws = (unsigned short*)d_ws;
    unsigned short* Qhi = ws;
    unsigned short* Khi = ws + SZP;
    unsigned short* Vt  = ws + 2 * SZP;
    float* out = (float*)d_out;

    sa_proj_kernel<<<256, 256, 0, stream>>>(x, wq, wk, wv, Qhi, Khi, Vt);
    sa_attn_kernel<<<256, 1024, 0, stream>>>(Qhi, Khi, Vt, out);
}